// Round 8
// baseline (91.712 us; speedup 1.0000x reference)
//
#include <hip/hip_runtime.h>

#define D 8
#define NE 4
#define NS 3
#define NI 5
#define LN_EPS 1e-5f

// weights-in-LDS float offsets (all 16B aligned)
#define OFF_W1 0      // NS*64  = 192
#define OFF_W2 192    // NS*32  = 96
#define OFF_B1 288    // NS*8   = 24
#define OFF_B2 312    // NS*4   = 12
#define OFF_C  324    // NS*32  = 96
#define OFF_WP 420    // NS*512 = 1536
#define WLDS_SIZE 1956

// ---------------------------------------------------------------------------
// Setup kernel: C[s][n][d] = bproj[s][d] + sum_ij Bmat[s][n][i][j]*Wproj[s][d][i*8+j]
// ---------------------------------------------------------------------------
__global__ void precompute_C_kernel(const float* __restrict__ Bmat,
                                    const float* __restrict__ Wproj,
                                    const float* __restrict__ bproj,
                                    float* __restrict__ C) {
    int idx = threadIdx.x;
    if (idx >= NS * NE * D) return;
    int s = idx / (NE * D);
    int rem = idx % (NE * D);
    int n = rem / D;
    int d = rem % D;
    const float* bm = Bmat + ((size_t)s * NE + n) * 64;
    const float* wp = Wproj + ((size_t)s * D + d) * 64;
    float acc = bproj[s * D + d];
    #pragma unroll
    for (int k = 0; k < 64; ++k) acc += bm[k] * wp[k];
    C[idx] = acc;
}

__device__ __forceinline__ float fast_tanh(float x) {
    float e = __expf(2.f * x);
    return 1.f - 2.f * __builtin_amdgcn_rcpf(e + 1.f);
}

// lane <-> lane^1 exchange via DPP quad_perm [1,0,3,2] (full-rate VALU)
__device__ __forceinline__ float xor1f(float x) {
    int i = __builtin_bit_cast(int, x);
    i = __builtin_amdgcn_mov_dpp(i, 0xB1, 0xF, 0xF, true);
    return __builtin_bit_cast(float, i);
}

__device__ __forceinline__ float4 ld4(const float* p) {
    return *reinterpret_cast<const float4*>(p);
}

// ---------------------------------------------------------------------------
// Main kernel: TWO lanes per row (lane parity p owns d-half {4p..4p+3}).
// Grid provides exactly 4 waves/SIMD, so clamp the backend's occupancy
// target with amdgpu_waves_per_eu(4,4): VGPR budget = 512/4 = 128, matching
// the ~118-float live set. (R7 failure: unbounded range -> backend targeted
// 8 waves/EU -> 64-VGPR budget -> ~29MB scratch spills at VGPR_Count=64.)
// Weights live in LDS (broadcast ds_read_b128, conflict-free); LICM of the
// ~112-float W1/W2/C loads is blocked by an opaque-zero pointer offset
// (NOT a memory clobber — that de-SROA'd the arrays in R6).
// ---------------------------------------------------------------------------
__global__ __attribute__((amdgpu_waves_per_eu(4, 4))) __launch_bounds__(256)
void whisp_kernel(
    const float* __restrict__ cl, const float* __restrict__ cd,
    const float* __restrict__ re_log, const float* __restrict__ mach,
    const float* __restrict__ alpha, const float* __restrict__ u,
    const float* __restrict__ We, const float* __restrict__ be,
    const float* __restrict__ Wproj,
    const float* __restrict__ Wr1, const float* __restrict__ br1,
    const float* __restrict__ Wr2, const float* __restrict__ br2,
    const float* __restrict__ ln_g, const float* __restrict__ ln_b,
    const float* __restrict__ Wout, const float* __restrict__ bout,
    const float* __restrict__ fg, const float* __restrict__ fb,
    const float* __restrict__ Wcst, const float* __restrict__ bcst,
    const float* __restrict__ Wcl, const float* __restrict__ bcl,
    const float* __restrict__ Cpre,
    float* __restrict__ out, int B)
{
    __shared__ __align__(16) float wlds[WLDS_SIZE];   // 7824 B
    __shared__ float souts[128 * 19];                 // 9728 B

    const int tid = threadIdx.x;
    const int p   = tid & 1;
    const int rl  = tid >> 1;
    const int row0 = blockIdx.x * 128 + rl;
    const bool active = (row0 < B);
    const int row = active ? row0 : (B - 1);
    const int d0  = p * 4;
    const int d0o = d0 ^ 4;

    // ---- stage loop weights into LDS (once per block) ----
    for (int i = tid; i < 192;  i += 256) wlds[OFF_W1 + i] = Wr1[i];
    for (int i = tid; i < 96;   i += 256) wlds[OFF_W2 + i] = Wr2[i];
    for (int i = tid; i < 24;   i += 256) wlds[OFF_B1 + i] = br1[i];
    for (int i = tid; i < 12;   i += 256) wlds[OFF_B2 + i] = br2[i];
    for (int i = tid; i < 96;   i += 256) wlds[OFF_C + i]  = Cpre[i];
    for (int i = tid; i < 1536; i += 256) wlds[OFF_WP + i] = Wproj[i];

    // ---- per-row inputs ----
    float uu[8];
    {
        const float4* up = reinterpret_cast<const float4*>(u + (size_t)row * D);
        float4 u0 = up[0], u1 = up[1];
        uu[0]=u0.x; uu[1]=u0.y; uu[2]=u0.z; uu[3]=u0.w;
        uu[4]=u1.x; uu[5]=u1.y; uu[6]=u1.z; uu[7]=u1.w;
    }
    float xs[NE] = { cl[row], cd[row], re_log[row], mach[row] };
    float al = alpha[row];

    // ---- embedding: E[n][dd] for my d-half ----
    float E[NE][4];
    #pragma unroll
    for (int n = 0; n < NE; ++n) {
        float4 wa = ld4(We + n * 16 + d0 * 2);
        float4 wb = ld4(We + n * 16 + d0 * 2 + 4);
        float4 bv = ld4(be + n * D + d0);
        E[n][0] = fast_tanh(fmaf(wa.x, xs[n], fmaf(wa.y, al, bv.x)));
        E[n][1] = fast_tanh(fmaf(wa.z, xs[n], fmaf(wa.w, al, bv.y)));
        E[n][2] = fast_tanh(fmaf(wb.x, xs[n], fmaf(wb.y, al, bv.z)));
        E[n][3] = fast_tanh(fmaf(wb.z, xs[n], fmaf(wb.w, al, bv.w)));
    }

    // LN params for my d-half (kernel-invariant)
    float lngv[4], lnbv[4];
    {
        float4 g = ld4(ln_g + d0), b = ld4(ln_b + d0);
        lngv[0]=g.x; lngv[1]=g.y; lngv[2]=g.z; lngv[3]=g.w;
        lnbv[0]=b.x; lnbv[1]=b.y; lnbv[2]=b.z; lnbv[3]=b.w;
    }

    __syncthreads();   // wlds ready

    int zero = 0;      // opaque 0, renewed each inner iteration

    // ---- outer stages ----
    #pragma unroll 1
    for (int s = 0; s < NS; ++s) {
        // t for my d-rows (full i), from LDS Wproj; once per stage
        const float* Wp = wlds + OFF_WP + s * 512;
        float tA[4][4], tB[4][4];
        #pragma unroll
        for (int dd = 0; dd < 4; ++dd) {
            #pragma unroll
            for (int k = 0; k < 4; ++k) {
                const float* wA = Wp + (d0 + dd) * 64 + (d0 + k) * 8;
                const float* wB = Wp + (d0 + dd) * 64 + (d0o + k) * 8;
                float4 a0v = ld4(wA), a1v = ld4(wA + 4);
                float4 b0v = ld4(wB), b1v = ld4(wB + 4);
                float a0 = uu[0] * a0v.x, a1 = uu[1] * a0v.y;
                a0 = fmaf(uu[2], a0v.z, a0); a1 = fmaf(uu[3], a0v.w, a1);
                a0 = fmaf(uu[4], a1v.x, a0); a1 = fmaf(uu[5], a1v.y, a1);
                a0 = fmaf(uu[6], a1v.z, a0); a1 = fmaf(uu[7], a1v.w, a1);
                tA[dd][k] = a0 + a1;
                float c0 = uu[0] * b0v.x, c1 = uu[1] * b0v.y;
                c0 = fmaf(uu[2], b0v.z, c0); c1 = fmaf(uu[3], b0v.w, c1);
                c0 = fmaf(uu[4], b1v.x, c0); c1 = fmaf(uu[5], b1v.y, c1);
                c0 = fmaf(uu[6], b1v.z, c0); c1 = fmaf(uu[7], b1v.w, c1);
                tB[dd][k] = c0 + c1;
            }
        }

        // per-stage biases: tiny (8 regs), hoisted out of the inner loop
        float b1a[4], b2a[4];
        {
            float4 b1q = ld4(wlds + OFF_B1 + s * 8 + d0);
            b1a[0]=b1q.x; b1a[1]=b1q.y; b1a[2]=b1q.z; b1a[3]=b1q.w;
            float4 b2q = ld4(wlds + OFF_B2 + s * 4);
            b2a[0]=b2q.x; b2a[1]=b2q.y; b2a[2]=b2q.z; b2a[3]=b2q.w;
        }

        for (int it = 0; it < NI; ++it) {
            // opaque zero: blocks LICM of the big LDS weight loads ONLY
            asm volatile("" : "+v"(zero));
            const float* W1z = wlds + OFF_W1 + s * 64 + zero;
            const float* W2z = wlds + OFF_W2 + s * 32 + zero;
            const float* Cz  = wlds + OFF_C  + s * 32 + zero;

            // H[n][dd] = C + E*tA + Eo*tB  (Eo transient per n)
            float H[NE][4];
            #pragma unroll
            for (int n = 0; n < NE; ++n) {
                float Eo0 = xor1f(E[n][0]), Eo1 = xor1f(E[n][1]);
                float Eo2 = xor1f(E[n][2]), Eo3 = xor1f(E[n][3]);
                float4 cv = ld4(Cz + n * D + d0);
                float cc[4] = { cv.x, cv.y, cv.z, cv.w };
                #pragma unroll
                for (int dd = 0; dd < 4; ++dd) {
                    float a0 = fmaf(E[n][0], tA[dd][0], cc[dd]);
                    float a1 = E[n][1] * tA[dd][1];
                    a0 = fmaf(E[n][2], tA[dd][2], a0);
                    a1 = fmaf(E[n][3], tA[dd][3], a1);
                    a0 = fmaf(Eo0, tB[dd][0], a0);
                    a1 = fmaf(Eo1, tB[dd][1], a1);
                    a0 = fmaf(Eo2, tB[dd][2], a0);
                    a1 = fmaf(Eo3, tB[dd][3], a1);
                    H[n][dd] = a0 + a1;
                }
            }

            // routing softmax per expert n
            float sm[NE][NE];
            #pragma unroll
            for (int n = 0; n < NE; ++n) {
                float Ho0 = xor1f(H[n][0]), Ho1 = xor1f(H[n][1]);
                float Ho2 = xor1f(H[n][2]), Ho3 = xor1f(H[n][3]);
                float r[4];
                #pragma unroll
                for (int dd = 0; dd < 4; ++dd) {
                    const float* w1r = W1z + (d0 + dd) * 8;
                    float4 wa = ld4(w1r + d0);
                    float4 wb = ld4(w1r + d0o);
                    float a0 = fmaf(H[n][0], wa.x, b1a[dd]);
                    float a1 = H[n][1] * wa.y;
                    a0 = fmaf(H[n][2], wa.z, a0);
                    a1 = fmaf(H[n][3], wa.w, a1);
                    a0 = fmaf(Ho0, wb.x, a0);
                    a1 = fmaf(Ho1, wb.y, a1);
                    a0 = fmaf(Ho2, wb.z, a0);
                    a1 = fmaf(Ho3, wb.w, a1);
                    r[dd] = fmaxf(a0 + a1, 0.f);
                }
                float lgp[4];
                #pragma unroll
                for (int e = 0; e < NE; ++e) {
                    float4 w2v = ld4(W2z + e * 8 + d0);
                    float a0 = r[0] * w2v.x;
                    float a1 = r[1] * w2v.y;
                    a0 = fmaf(r[2], w2v.z, a0);
                    a1 = fmaf(r[3], w2v.w, a1);
                    lgp[e] = a0 + a1;
                }
                float lg0 = lgp[0] + xor1f(lgp[0]) + b2a[0];
                float lg1 = lgp[1] + xor1f(lgp[1]) + b2a[1];
                float lg2 = lgp[2] + xor1f(lgp[2]) + b2a[2];
                float lg3 = lgp[3] + xor1f(lgp[3]) + b2a[3];
                float mx = fmaxf(fmaxf(lg0, lg1), fmaxf(lg2, lg3));
                float e0 = __expf(lg0 - mx), e1 = __expf(lg1 - mx);
                float e2 = __expf(lg2 - mx), e3 = __expf(lg3 - mx);
                float inv = __builtin_amdgcn_rcpf((e0 + e1) + (e2 + e3));
                sm[n][0] = e0 * inv; sm[n][1] = e1 * inv;
                sm[n][2] = e2 * inv; sm[n][3] = e3 * inv;
            }

            // E += mix (H stored by d-half: all local)
            #pragma unroll
            for (int n = 0; n < NE; ++n) {
                #pragma unroll
                for (int dd = 0; dd < 4; ++dd) {
                    float a0 = fmaf(sm[n][0], H[0][dd], E[n][dd]);
                    float a1 = sm[n][1] * H[1][dd];
                    a0 = fmaf(sm[n][2], H[2][dd], a0);
                    a1 = fmaf(sm[n][3], H[3][dd], a1);
                    E[n][dd] = a0 + a1;
                }
            }
        }

        // post-stage LayerNorm (cross-lane sums via DPP)
        #pragma unroll
        for (int n = 0; n < NE; ++n) {
            float sl = (E[n][0] + E[n][1]) + (E[n][2] + E[n][3]);
            float m = (sl + xor1f(sl)) * 0.125f;
            float c0 = E[n][0] - m, c1 = E[n][1] - m;
            float c2 = E[n][2] - m, c3 = E[n][3] - m;
            float vl = fmaf(c0, c0, c1 * c1) + fmaf(c2, c2, c3 * c3);
            float v = (vl + xor1f(vl)) * 0.125f;
            float inv = __builtin_amdgcn_rsqf(v + LN_EPS);
            E[n][0] = fmaf(c0 * inv, lngv[0], lnbv[0]);
            E[n][1] = fmaf(c1 * inv, lngv[1], lnbv[1]);
            E[n][2] = fmaf(c2 * inv, lngv[2], lnbv[2]);
            E[n][3] = fmaf(c3 * inv, lngv[3], lnbv[3]);
        }
    }

    // ---- final mixing (weights from global; one-time, post-loop) ----
    float w0, w1, w2, w3;
    {
        float lgo[NE];
        #pragma unroll
        for (int e = 0; e < NE; ++e) {
            float a0 = 0.f, a1 = 0.f;
            #pragma unroll
            for (int n = 0; n < NE; ++n) {
                float4 wv = ld4(Wout + e * 32 + n * D + d0);
                a0 = fmaf(E[n][0], wv.x, a0);
                a1 = fmaf(E[n][1], wv.y, a1);
                a0 = fmaf(E[n][2], wv.z, a0);
                a1 = fmaf(E[n][3], wv.w, a1);
            }
            float part = a0 + a1;
            lgo[e] = part + xor1f(part) + bout[e];
        }
        float mx = fmaxf(fmaxf(lgo[0], lgo[1]), fmaxf(lgo[2], lgo[3]));
        w0 = __expf(lgo[0] - mx); w1 = __expf(lgo[1] - mx);
        w2 = __expf(lgo[2] - mx); w3 = __expf(lgo[3] - mx);
        float winv = __builtin_amdgcn_rcpf((w0 + w1) + (w2 + w3));
        w0 *= winv; w1 *= winv; w2 *= winv; w3 *= winv;
    }

    float z[4];
    #pragma unroll
    for (int dd = 0; dd < 4; ++dd) {
        float a0 = w0 * E[0][dd];
        float a1 = w1 * E[1][dd];
        a0 = fmaf(w2, E[2][dd], a0);
        a1 = fmaf(w3, E[3][dd], a1);
        z[dd] = a0 + a1;
    }
    {
        float sl = (z[0] + z[1]) + (z[2] + z[3]);
        float zm = (sl + xor1f(sl)) * 0.125f;
        float c0 = z[0] - zm, c1 = z[1] - zm, c2 = z[2] - zm, c3 = z[3] - zm;
        float vl = fmaf(c0, c0, c1 * c1) + fmaf(c2, c2, c3 * c3);
        float zv = (vl + xor1f(vl)) * 0.125f;
        float zinv = __builtin_amdgcn_rsqf(zv + LN_EPS);
        float4 g = ld4(fg + d0), b = ld4(fb + d0);
        z[0] = fmaf(c0 * zinv, g.x, b.x);
        z[1] = fmaf(c1 * zinv, g.y, b.y);
        z[2] = fmaf(c2 * zinv, g.z, b.z);
        z[3] = fmaf(c3 * zinv, g.w, b.w);
    }

    // heads: partial over my d-half, DPP-reduce, lane writes its k-parity
    #pragma unroll
    for (int k = 0; k < 18; ++k) {
        float4 wv = ld4(Wcst + k * D + d0);
        float a0 = z[0] * wv.x;
        float a1 = z[1] * wv.y;
        a0 = fmaf(z[2], wv.z, a0);
        a1 = fmaf(z[3], wv.w, a1);
        float part = a0 + a1;
        float full = part + xor1f(part) + bcst[k];
        if (active && ((k & 1) == p)) souts[rl * 19 + k] = full;
    }
    {
        float4 wv = ld4(Wcl + d0);
        float a0 = z[0] * wv.x;
        float a1 = z[1] * wv.y;
        a0 = fmaf(z[2], wv.z, a0);
        a1 = fmaf(z[3], wv.w, a1);
        float part = a0 + a1;
        float full = part + xor1f(part) + bcl[0];
        if (active && (p == 0)) souts[rl * 19 + 18] = full;
    }

    __syncthreads();

    // coalesced writeback of this block's 128x19 outputs
    const int base = blockIdx.x * 128;
    int nrows = B - base;
    if (nrows > 128) nrows = 128;
    if (nrows > 0) {
        const int cnt = nrows * 19;
        for (int i = tid; i < cnt; i += 256)
            out[(size_t)base * 19 + i] = souts[i];
    }
}

extern "C" void kernel_launch(void* const* d_in, const int* in_sizes, int n_in,
                              void* d_out, int out_size, void* d_ws, size_t ws_size,
                              hipStream_t stream) {
    const float* cl     = (const float*)d_in[0];
    const float* cd     = (const float*)d_in[1];
    const float* re_log = (const float*)d_in[2];
    const float* mach   = (const float*)d_in[3];
    const float* alpha  = (const float*)d_in[4];
    const float* u      = (const float*)d_in[5];
    const float* We     = (const float*)d_in[6];
    const float* be     = (const float*)d_in[7];
    const float* Bmat   = (const float*)d_in[8];
    const float* Wproj  = (const float*)d_in[9];
    const float* bproj  = (const float*)d_in[10];
    const float* Wr1    = (const float*)d_in[11];
    const float* br1    = (const float*)d_in[12];
    const float* Wr2    = (const float*)d_in[13];
    const float* br2    = (const float*)d_in[14];
    const float* ln_g   = (const float*)d_in[15];
    const float* ln_b   = (const float*)d_in[16];
    const float* Wout   = (const float*)d_in[17];
    const float* bout   = (const float*)d_in[18];
    const float* fg     = (const float*)d_in[19];
    const float* fb     = (const float*)d_in[20];
    const float* Wcst   = (const float*)d_in[21];
    const float* bcst   = (const float*)d_in[22];
    const float* Wcl    = (const float*)d_in[23];
    const float* bcl    = (const float*)d_in[24];

    float* Cpre = (float*)d_ws;   // 96 floats
    const int B = in_sizes[0];

    hipLaunchKernelGGL(precompute_C_kernel, dim3(1), dim3(128), 0, stream,
                       Bmat, Wproj, bproj, Cpre);

    const int blocks = (B + 127) / 128;   // 128 rows per 256-thread block
    hipLaunchKernelGGL(whisp_kernel, dim3(blocks), dim3(256), 0, stream,
                       cl, cd, re_log, mach, alpha, u, We, be, Wproj,
                       Wr1, br1, Wr2, br2, ln_g, ln_b, Wout, bout, fg, fb,
                       Wcst, bcst, Wcl, bcl, Cpre, (float*)d_out, B);
}

// Round 9
// 72.293 us; speedup vs baseline: 1.2686x; 1.2686x over previous
//
#include <hip/hip_runtime.h>

#define D 8
#define NE 4
#define NS 3
#define NI 5
#define LN_EPS 1e-5f

// weights-in-LDS float offsets (16B-aligned sections)
#define OFF_W1 0      // NS*64  = 192
#define OFF_W2 192    // NS*32  = 96
#define OFF_B1 288    // NS*8   = 24
#define OFF_B2 312    // NS*4   = 12
#define OFF_C  324    // NS*32  = 96
#define OFF_LN 420    // 16 (ln_g, ln_b)
#define OFF_WP 436    // NS*512 = 1536
#define WLDS_SIZE 1972

// ---------------------------------------------------------------------------
// Setup kernel: C[s][n][d] = bproj[s][d] + sum_ij Bmat[s][n][i][j]*Wproj[s][d][i*8+j]
// ---------------------------------------------------------------------------
__global__ void precompute_C_kernel(const float* __restrict__ Bmat,
                                    const float* __restrict__ Wproj,
                                    const float* __restrict__ bproj,
                                    float* __restrict__ C) {
    int idx = threadIdx.x;
    if (idx >= NS * NE * D) return;
    int s = idx / (NE * D);
    int rem = idx % (NE * D);
    int n = rem / D;
    int d = rem % D;
    const float* bm = Bmat + ((size_t)s * NE + n) * 64;
    const float* wp = Wproj + ((size_t)s * D + d) * 64;
    float acc = bproj[s * D + d];
    #pragma unroll
    for (int k = 0; k < 64; ++k) acc += bm[k] * wp[k];
    C[idx] = acc;
}

__device__ __forceinline__ float fast_tanh(float x) {
    float e = __expf(2.f * x);
    return 1.f - 2.f * __builtin_amdgcn_rcpf(e + 1.f);
}

__device__ __forceinline__ float4 ld4(const float* p) {
    return *reinterpret_cast<const float4*>(p);
}

// ---------------------------------------------------------------------------
// Main kernel: ONE thread per row (R2 skeleton — the only config the backend
// allocates cleanly: (256,2) -> 128 VGPR, no scratch). Hot-loop weights live
// in LDS and are read as wave-uniform broadcast ds_read_b128 (in-order,
// immediate-offset addressing) instead of R2's ~140 per-lane global loads
// per iteration. t[8][8] in per-thread LDS float4 chunks (R2-proven,
// conflict-free). LICM of weight loads blocked by opaque-zero (R7-proven;
// NOT a memory clobber, which de-SROA'd arrays in R6). LN params re-read
// from LDS per stage to keep inner-loop live set ~120 < 128.
// ---------------------------------------------------------------------------
__global__ __launch_bounds__(256, 2) void whisp_kernel(
    const float* __restrict__ cl, const float* __restrict__ cd,
    const float* __restrict__ re_log, const float* __restrict__ mach,
    const float* __restrict__ alpha, const float* __restrict__ u,
    const float* __restrict__ We, const float* __restrict__ be,
    const float* __restrict__ Wproj,
    const float* __restrict__ Wr1, const float* __restrict__ br1,
    const float* __restrict__ Wr2, const float* __restrict__ br2,
    const float* __restrict__ ln_g, const float* __restrict__ ln_b,
    const float* __restrict__ Wout, const float* __restrict__ bout,
    const float* __restrict__ fg, const float* __restrict__ fb,
    const float* __restrict__ Wcst, const float* __restrict__ bcst,
    const float* __restrict__ Wcl, const float* __restrict__ bcl,
    const float* __restrict__ Cpre,
    float* __restrict__ out, int B)
{
    __shared__ __align__(16) float wlds[WLDS_SIZE];   // 7888 B
    __shared__ __align__(16) float4 tbuf[16 * 256];   // 64 KB; reused as souts

    const int tid = threadIdx.x;
    const int row0 = blockIdx.x * 256 + tid;
    const bool active = (row0 < B);
    const int row = active ? row0 : (B - 1);

    // ---- stage all hot-loop weights into LDS (once per block) ----
    for (int i = tid; i < 192;  i += 256) wlds[OFF_W1 + i] = Wr1[i];
    for (int i = tid; i < 96;   i += 256) wlds[OFF_W2 + i] = Wr2[i];
    for (int i = tid; i < 24;   i += 256) wlds[OFF_B1 + i] = br1[i];
    for (int i = tid; i < 12;   i += 256) wlds[OFF_B2 + i] = br2[i];
    for (int i = tid; i < 96;   i += 256) wlds[OFF_C + i]  = Cpre[i];
    for (int i = tid; i < 8;    i += 256) { wlds[OFF_LN + i] = ln_g[i]; wlds[OFF_LN + 8 + i] = ln_b[i]; }
    for (int i = tid; i < 1536; i += 256) wlds[OFF_WP + i] = Wproj[i];

    // ---- per-row inputs ----
    float uu[D];
    {
        const float4* up = reinterpret_cast<const float4*>(u + (size_t)row * D);
        float4 u0 = up[0], u1 = up[1];
        uu[0]=u0.x; uu[1]=u0.y; uu[2]=u0.z; uu[3]=u0.w;
        uu[4]=u1.x; uu[5]=u1.y; uu[6]=u1.z; uu[7]=u1.w;
    }
    float xs[NE] = { cl[row], cd[row], re_log[row], mach[row] };
    float al = alpha[row];

    // ---- embedding (one-time global) ----
    float E[NE][D];
    #pragma unroll
    for (int n = 0; n < NE; ++n) {
        #pragma unroll
        for (int d = 0; d < D; ++d) {
            float pre = We[n * 16 + d * 2 + 0] * xs[n]
                      + We[n * 16 + d * 2 + 1] * al
                      + be[n * D + d];
            E[n][d] = fast_tanh(pre);
        }
    }

    __syncthreads();   // wlds ready

    int zero = 0;      // opaque 0, renewed each inner iteration

    // ---- outer stages ----
    #pragma unroll 1
    for (int s = 0; s < NS; ++s) {
        // t[d][i] = sum_j u[j]*Wp[d][i*8+j] from LDS broadcast -> tbuf chunks
        {
            const float* Wp = wlds + OFF_WP + s * 512;
            #pragma unroll
            for (int d = 0; d < D; ++d) {
                float tv[D];
                #pragma unroll
                for (int i = 0; i < D; ++i) {
                    float4 wa = ld4(Wp + d * 64 + i * 8);
                    float4 wb = ld4(Wp + d * 64 + i * 8 + 4);
                    float a0 = uu[0] * wa.x, a1 = uu[1] * wa.y;
                    a0 = fmaf(uu[2], wa.z, a0); a1 = fmaf(uu[3], wa.w, a1);
                    a0 = fmaf(uu[4], wb.x, a0); a1 = fmaf(uu[5], wb.y, a1);
                    a0 = fmaf(uu[6], wb.z, a0); a1 = fmaf(uu[7], wb.w, a1);
                    tv[i] = a0 + a1;
                }
                tbuf[(2 * d) * 256 + tid]     = make_float4(tv[0], tv[1], tv[2], tv[3]);
                tbuf[(2 * d + 1) * 256 + tid] = make_float4(tv[4], tv[5], tv[6], tv[7]);
            }
        }

        // per-stage biases (12 regs, hoisted)
        float b1a[8], b2a[4];
        {
            float4 q0 = ld4(wlds + OFF_B1 + s * 8);
            float4 q1 = ld4(wlds + OFF_B1 + s * 8 + 4);
            b1a[0]=q0.x; b1a[1]=q0.y; b1a[2]=q0.z; b1a[3]=q0.w;
            b1a[4]=q1.x; b1a[5]=q1.y; b1a[6]=q1.z; b1a[7]=q1.w;
            float4 q2 = ld4(wlds + OFF_B2 + s * 4);
            b2a[0]=q2.x; b2a[1]=q2.y; b2a[2]=q2.z; b2a[3]=q2.w;
        }

        #pragma unroll 1
        for (int it = 0; it < NI; ++it) {
            // opaque zero: makes weight addresses loop-variant (blocks LICM)
            asm volatile("" : "+v"(zero));
            const float*  W1z = wlds + OFF_W1 + s * 64 + zero;
            const float*  W2z = wlds + OFF_W2 + s * 32 + zero;
            const float*  Cz  = wlds + OFF_C  + s * 32 + zero;
            const float4* tz  = tbuf + tid + zero;

            // H init from C (broadcast b128)
            float H[NE][D];
            #pragma unroll
            for (int n = 0; n < NE; ++n) {
                float4 c0 = ld4(Cz + n * 8);
                float4 c1 = ld4(Cz + n * 8 + 4);
                H[n][0]=c0.x; H[n][1]=c0.y; H[n][2]=c0.z; H[n][3]=c0.w;
                H[n][4]=c1.x; H[n][5]=c1.y; H[n][6]=c1.z; H[n][7]=c1.w;
            }
            // H += E * t (t per-thread chunks)
            #pragma unroll
            for (int d = 0; d < D; ++d) {
                float4 ta = tz[(2 * d) * 256];
                float4 tb = tz[(2 * d + 1) * 256];
                #pragma unroll
                for (int n = 0; n < NE; ++n) {
                    float a0 = fmaf(E[n][0], ta.x, H[n][d]);
                    float a1 = E[n][1] * ta.y;
                    a0 = fmaf(E[n][2], ta.z, a0);
                    a1 = fmaf(E[n][3], ta.w, a1);
                    a0 = fmaf(E[n][4], tb.x, a0);
                    a1 = fmaf(E[n][5], tb.y, a1);
                    a0 = fmaf(E[n][6], tb.z, a0);
                    a1 = fmaf(E[n][7], tb.w, a1);
                    H[n][d] = a0 + a1;
                }
            }

            // routing softmax per expert n (W1/W2 broadcast; r/lg transient)
            float sm[NE][NE];
            #pragma unroll
            for (int n = 0; n < NE; ++n) {
                float r[D];
                #pragma unroll
                for (int d = 0; d < D; ++d) {
                    float4 wa = ld4(W1z + d * 8);
                    float4 wb = ld4(W1z + d * 8 + 4);
                    float a0 = fmaf(H[n][0], wa.x, b1a[d]);
                    float a1 = H[n][1] * wa.y;
                    a0 = fmaf(H[n][2], wa.z, a0);
                    a1 = fmaf(H[n][3], wa.w, a1);
                    a0 = fmaf(H[n][4], wb.x, a0);
                    a1 = fmaf(H[n][5], wb.y, a1);
                    a0 = fmaf(H[n][6], wb.z, a0);
                    a1 = fmaf(H[n][7], wb.w, a1);
                    r[d] = fmaxf(a0 + a1, 0.f);
                }
                float lg[NE];
                #pragma unroll
                for (int e = 0; e < NE; ++e) {
                    float4 wa = ld4(W2z + e * 8);
                    float4 wb = ld4(W2z + e * 8 + 4);
                    float a0 = fmaf(r[0], wa.x, b2a[e]);
                    float a1 = r[1] * wa.y;
                    a0 = fmaf(r[2], wa.z, a0);
                    a1 = fmaf(r[3], wa.w, a1);
                    a0 = fmaf(r[4], wb.x, a0);
                    a1 = fmaf(r[5], wb.y, a1);
                    a0 = fmaf(r[6], wb.z, a0);
                    a1 = fmaf(r[7], wb.w, a1);
                    lg[e] = a0 + a1;
                }
                float mx = fmaxf(fmaxf(lg[0], lg[1]), fmaxf(lg[2], lg[3]));
                float e0 = __expf(lg[0] - mx), e1 = __expf(lg[1] - mx);
                float e2 = __expf(lg[2] - mx), e3 = __expf(lg[3] - mx);
                float inv = __builtin_amdgcn_rcpf((e0 + e1) + (e2 + e3));
                sm[n][0] = e0 * inv; sm[n][1] = e1 * inv;
                sm[n][2] = e2 * inv; sm[n][3] = e3 * inv;
            }

            // E += mix
            #pragma unroll
            for (int n = 0; n < NE; ++n) {
                #pragma unroll
                for (int d = 0; d < D; ++d) {
                    float a0 = fmaf(sm[n][0], H[0][d], E[n][d]);
                    float a1 = sm[n][1] * H[1][d];
                    a0 = fmaf(sm[n][2], H[2][d], a0);
                    a1 = fmaf(sm[n][3], H[3][d], a1);
                    E[n][d] = a0 + a1;
                }
            }
        }

        // post-stage LayerNorm (params from LDS per stage: not live in loop)
        float lngv[8], lnbv[8];
        {
            float4 g0 = ld4(wlds + OFF_LN),     g1 = ld4(wlds + OFF_LN + 4);
            float4 b0 = ld4(wlds + OFF_LN + 8), b1 = ld4(wlds + OFF_LN + 12);
            lngv[0]=g0.x; lngv[1]=g0.y; lngv[2]=g0.z; lngv[3]=g0.w;
            lngv[4]=g1.x; lngv[5]=g1.y; lngv[6]=g1.z; lngv[7]=g1.w;
            lnbv[0]=b0.x; lnbv[1]=b0.y; lnbv[2]=b0.z; lnbv[3]=b0.w;
            lnbv[4]=b1.x; lnbv[5]=b1.y; lnbv[6]=b1.z; lnbv[7]=b1.w;
        }
        #pragma unroll
        for (int n = 0; n < NE; ++n) {
            float m = 0.f;
            #pragma unroll
            for (int d = 0; d < D; ++d) m += E[n][d];
            m *= (1.f / D);
            float v = 0.f;
            #pragma unroll
            for (int d = 0; d < D; ++d) { float c = E[n][d] - m; v = fmaf(c, c, v); }
            v *= (1.f / D);
            float inv = __builtin_amdgcn_rsqf(v + LN_EPS);
            #pragma unroll
            for (int d = 0; d < D; ++d)
                E[n][d] = (E[n][d] - m) * inv * lngv[d] + lnbv[d];
        }
    }

    // ---- final mixing (one-time global weights) ----
    float lgf[NE];
    #pragma unroll
    for (int e = 0; e < NE; ++e) {
        float a0 = bout[e], a1 = 0.f;
        #pragma unroll
        for (int n = 0; n < NE; ++n) {
            #pragma unroll
            for (int d = 0; d < D; d += 2) {
                a0 = fmaf(E[n][d],     Wout[e * 32 + n * D + d],     a0);
                a1 = fmaf(E[n][d + 1], Wout[e * 32 + n * D + d + 1], a1);
            }
        }
        lgf[e] = a0 + a1;
    }
    float mx = fmaxf(fmaxf(lgf[0], lgf[1]), fmaxf(lgf[2], lgf[3]));
    float w0 = __expf(lgf[0] - mx), w1 = __expf(lgf[1] - mx);
    float w2 = __expf(lgf[2] - mx), w3 = __expf(lgf[3] - mx);
    float winv = __builtin_amdgcn_rcpf((w0 + w1) + (w2 + w3));
    w0 *= winv; w1 *= winv; w2 *= winv; w3 *= winv;

    float z[D];
    #pragma unroll
    for (int d = 0; d < D; ++d) {
        float a0 = w0 * E[0][d];
        float a1 = w1 * E[1][d];
        a0 = fmaf(w2, E[2][d], a0);
        a1 = fmaf(w3, E[3][d], a1);
        z[d] = a0 + a1;
    }
    float zm = 0.f;
    #pragma unroll
    for (int d = 0; d < D; ++d) zm += z[d];
    zm *= (1.f / D);
    float zv = 0.f;
    #pragma unroll
    for (int d = 0; d < D; ++d) { float c = z[d] - zm; zv = fmaf(c, c, zv); }
    zv *= (1.f / D);
    float zinv = __builtin_amdgcn_rsqf(zv + LN_EPS);
    #pragma unroll
    for (int d = 0; d < D; ++d)
        z[d] = (z[d] - zm) * zinv * fg[d] + fb[d];

    // heads
    float zout[19];
    #pragma unroll
    for (int k = 0; k < 18; ++k) {
        float a0 = bcst[k], a1 = 0.f;
        #pragma unroll
        for (int d = 0; d < D; d += 2) {
            a0 = fmaf(z[d],     Wcst[k * D + d],     a0);
            a1 = fmaf(z[d + 1], Wcst[k * D + d + 1], a1);
        }
        zout[k] = a0 + a1;
    }
    {
        float a0 = bcl[0], a1 = 0.f;
        #pragma unroll
        for (int d = 0; d < D; d += 2) {
            a0 = fmaf(z[d],     Wcl[d],     a0);
            a1 = fmaf(z[d + 1], Wcl[d + 1], a1);
        }
        zout[18] = a0 + a1;
    }

    // tbuf is dead; reuse as souts (barrier: other threads' chunk columns)
    __syncthreads();
    float* souts = reinterpret_cast<float*>(tbuf);
    if (active) {
        #pragma unroll
        for (int k = 0; k < 19; ++k) souts[tid * 19 + k] = zout[k];
    }
    __syncthreads();

    // coalesced writeback of this block's 256x19 outputs
    const int base = blockIdx.x * 256;
    int nrows = B - base;
    if (nrows > 256) nrows = 256;
    if (nrows > 0) {
        const int cnt = nrows * 19;
        for (int i = tid; i < cnt; i += 256)
            out[(size_t)base * 19 + i] = souts[i];
    }
}

extern "C" void kernel_launch(void* const* d_in, const int* in_sizes, int n_in,
                              void* d_out, int out_size, void* d_ws, size_t ws_size,
                              hipStream_t stream) {
    const float* cl     = (const float*)d_in[0];
    const float* cd     = (const float*)d_in[1];
    const float* re_log = (const float*)d_in[2];
    const float* mach   = (const float*)d_in[3];
    const float* alpha  = (const float*)d_in[4];
    const float* u      = (const float*)d_in[5];
    const float* We     = (const float*)d_in[6];
    const float* be     = (const float*)d_in[7];
    const float* Bmat   = (const float*)d_in[8];
    const float* Wproj  = (const float*)d_in[9];
    const float* bproj  = (const float*)d_in[10];
    const float* Wr1    = (const float*)d_in[11];
    const float* br1    = (const float*)d_in[12];
    const float* Wr2    = (const float*)d_in[13];
    const float* br2    = (const float*)d_in[14];
    const float* ln_g   = (const float*)d_in[15];
    const float* ln_b   = (const float*)d_in[16];
    const float* Wout   = (const float*)d_in[17];
    const float* bout   = (const float*)d_in[18];
    const float* fg     = (const float*)d_in[19];
    const float* fb     = (const float*)d_in[20];
    const float* Wcst   = (const float*)d_in[21];
    const float* bcst   = (const float*)d_in[22];
    const float* Wcl    = (const float*)d_in[23];
    const float* bcl    = (const float*)d_in[24];

    float* Cpre = (float*)d_ws;   // 96 floats
    const int B = in_sizes[0];

    hipLaunchKernelGGL(precompute_C_kernel, dim3(1), dim3(128), 0, stream,
                       Bmat, Wproj, bproj, Cpre);

    const int blocks = (B + 255) / 256;
    hipLaunchKernelGGL(whisp_kernel, dim3(blocks), dim3(256), 0, stream,
                       cl, cd, re_log, mach, alpha, u, We, be, Wproj,
                       Wr1, br1, Wr2, br2, ln_g, ln_b, Wout, bout, fg, fb,
                       Wcst, bcst, Wcl, bcl, Cpre, (float*)d_out, B);
}

// Round 10
// 65.208 us; speedup vs baseline: 1.4065x; 1.1087x over previous
//
#include <hip/hip_runtime.h>

#define D 8
#define NE 4
#define NS 3
#define NI 5
#define LN_EPS 1e-5f

// weights-in-LDS float offsets (16B-aligned sections)
#define OFF_W1  0      // NS*64  = 192 (natural [s][d][k])
#define OFF_W2T 192    // NS*32  = 96  (transposed [s][d][e])
#define OFF_B1  288    // NS*8   = 24
#define OFF_B2  312    // NS*4   = 12
#define OFF_C   324    // NS*32  = 96  (n-paired [s][nn][d][f], from precompute)
#define OFF_LN  420    // 16 (ln_g, ln_b)
#define OFF_WP  436    // NS*512 = 1536 (natural)
#define WLDS_SIZE 1972

typedef float f2 __attribute__((ext_vector_type(2)));

__device__ __forceinline__ f2 fma2(f2 a, f2 b, f2 c) { return __builtin_elementwise_fma(a, b, c); }
__device__ __forceinline__ f2 max2(f2 a, f2 b) { return __builtin_elementwise_max(a, b); }
__device__ __forceinline__ f2 bc(float s) { return (f2){s, s}; }

// ---------------------------------------------------------------------------
// Setup kernel: writes C in n-PAIRED layout: C[s*32 + ((n>>1)*8 + d)*2 + (n&1)]
// ---------------------------------------------------------------------------
__global__ void precompute_C_kernel(const float* __restrict__ Bmat,
                                    const float* __restrict__ Wproj,
                                    const float* __restrict__ bproj,
                                    float* __restrict__ C) {
    int idx = threadIdx.x;
    if (idx >= NS * NE * D) return;
    int s = idx / (NE * D);
    int rem = idx % (NE * D);
    int n = rem / D;
    int d = rem % D;
    const float* bm = Bmat + ((size_t)s * NE + n) * 64;
    const float* wp = Wproj + ((size_t)s * D + d) * 64;
    float acc = bproj[s * D + d];
    #pragma unroll
    for (int k = 0; k < 64; ++k) acc += bm[k] * wp[k];
    C[s * 32 + ((n >> 1) * 8 + d) * 2 + (n & 1)] = acc;
}

__device__ __forceinline__ float fast_tanh(float x) {
    float e = __expf(2.f * x);
    return 1.f - 2.f * __builtin_amdgcn_rcpf(e + 1.f);
}

__device__ __forceinline__ float4 ld4(const float* p) {
    return *reinterpret_cast<const float4*>(p);
}

// ---------------------------------------------------------------------------
// Main kernel: ONE thread per row (R9 skeleton: (256,2) -> clean 128-VGPR
// allocation, weights in LDS, opaque-zero LICM gate). NEW in R10:
//  (a) all row-state paired over n (f2) -> v_pk_fma_f32 (gfx950 full-rate
//      packed fp32) halves VALU issue for every matvec;
//  (b) r->lg fused per-d so W1/W2 rows are read ONCE per iteration, not per
//      expert: 120 -> 48 ds_read_b128/iter (LDS pipe was co-bottleneck).
// ---------------------------------------------------------------------------
__global__ __launch_bounds__(256, 2) void whisp_kernel(
    const float* __restrict__ cl, const float* __restrict__ cd,
    const float* __restrict__ re_log, const float* __restrict__ mach,
    const float* __restrict__ alpha, const float* __restrict__ u,
    const float* __restrict__ We, const float* __restrict__ be,
    const float* __restrict__ Wproj,
    const float* __restrict__ Wr1, const float* __restrict__ br1,
    const float* __restrict__ Wr2, const float* __restrict__ br2,
    const float* __restrict__ ln_g, const float* __restrict__ ln_b,
    const float* __restrict__ Wout, const float* __restrict__ bout,
    const float* __restrict__ fg, const float* __restrict__ fb,
    const float* __restrict__ Wcst, const float* __restrict__ bcst,
    const float* __restrict__ Wcl, const float* __restrict__ bcl,
    const float* __restrict__ Cpre,
    float* __restrict__ out, int B)
{
    __shared__ __align__(16) float wlds[WLDS_SIZE];   // 7888 B
    __shared__ __align__(16) float4 tbuf[16 * 256];   // 64 KB; reused as souts

    const int tid = threadIdx.x;
    const int row0 = blockIdx.x * 256 + tid;
    const bool active = (row0 < B);
    const int row = active ? row0 : (B - 1);

    // ---- stage hot-loop weights into LDS (once per block) ----
    for (int i = tid; i < 192;  i += 256) wlds[OFF_W1 + i] = Wr1[i];     // natural
    for (int i = tid; i < 96;   i += 256) {                              // W2 -> [s][d][e]
        int s = i / 32, rem = i % 32, d = rem / 4, e = rem % 4;
        wlds[OFF_W2T + i] = Wr2[s * 32 + e * 8 + d];
    }
    for (int i = tid; i < 24;   i += 256) wlds[OFF_B1 + i] = br1[i];
    for (int i = tid; i < 12;   i += 256) wlds[OFF_B2 + i] = br2[i];
    for (int i = tid; i < 96;   i += 256) wlds[OFF_C + i]  = Cpre[i];    // already n-paired
    for (int i = tid; i < 8;    i += 256) { wlds[OFF_LN + i] = ln_g[i]; wlds[OFF_LN + 8 + i] = ln_b[i]; }
    for (int i = tid; i < 1536; i += 256) wlds[OFF_WP + i] = Wproj[i];

    // ---- per-row inputs ----
    float uu[D];
    {
        const float4* up = reinterpret_cast<const float4*>(u + (size_t)row * D);
        float4 u0 = up[0], u1 = up[1];
        uu[0]=u0.x; uu[1]=u0.y; uu[2]=u0.z; uu[3]=u0.w;
        uu[4]=u1.x; uu[5]=u1.y; uu[6]=u1.z; uu[7]=u1.w;
    }
    float xs[NE] = { cl[row], cd[row], re_log[row], mach[row] };
    float al = alpha[row];

    // ---- embedding -> E2[nn][d] = (E[2nn][d], E[2nn+1][d]) ----
    f2 E2[2][D];
    #pragma unroll
    for (int nn = 0; nn < 2; ++nn) {
        #pragma unroll
        for (int d = 0; d < D; ++d) {
            int na = 2 * nn, nb = 2 * nn + 1;
            float pa = We[na * 16 + d * 2] * xs[na] + We[na * 16 + d * 2 + 1] * al + be[na * D + d];
            float pb = We[nb * 16 + d * 2] * xs[nb] + We[nb * 16 + d * 2 + 1] * al + be[nb * D + d];
            E2[nn][d] = (f2){ fast_tanh(pa), fast_tanh(pb) };
        }
    }

    __syncthreads();   // wlds ready

    int zero = 0;      // opaque 0: blocks LICM of weight loads (R7-proven)

    // ---- outer stages ----
    #pragma unroll 1
    for (int s = 0; s < NS; ++s) {
        // t[d][i] = sum_j u[j]*Wp[d][i*8+j] -> per-thread LDS chunks
        {
            const float* Wp = wlds + OFF_WP + s * 512;
            f2 uu2[4] = { {uu[0],uu[1]}, {uu[2],uu[3]}, {uu[4],uu[5]}, {uu[6],uu[7]} };
            #pragma unroll
            for (int d = 0; d < D; ++d) {
                float tv[D];
                #pragma unroll
                for (int i = 0; i < D; ++i) {
                    float4 wa = ld4(Wp + d * 64 + i * 8);
                    float4 wb = ld4(Wp + d * 64 + i * 8 + 4);
                    f2 acc = uu2[0] * (f2){wa.x, wa.y};
                    acc = fma2(uu2[1], (f2){wa.z, wa.w}, acc);
                    acc = fma2(uu2[2], (f2){wb.x, wb.y}, acc);
                    acc = fma2(uu2[3], (f2){wb.z, wb.w}, acc);
                    tv[i] = acc.x + acc.y;
                }
                tbuf[(2 * d) * 256 + tid]     = make_float4(tv[0], tv[1], tv[2], tv[3]);
                tbuf[(2 * d + 1) * 256 + tid] = make_float4(tv[4], tv[5], tv[6], tv[7]);
            }
        }

        // per-stage biases (12 regs)
        float b1a[8], b2a[4];
        {
            float4 q0 = ld4(wlds + OFF_B1 + s * 8);
            float4 q1 = ld4(wlds + OFF_B1 + s * 8 + 4);
            b1a[0]=q0.x; b1a[1]=q0.y; b1a[2]=q0.z; b1a[3]=q0.w;
            b1a[4]=q1.x; b1a[5]=q1.y; b1a[6]=q1.z; b1a[7]=q1.w;
            float4 q2 = ld4(wlds + OFF_B2 + s * 4);
            b2a[0]=q2.x; b2a[1]=q2.y; b2a[2]=q2.z; b2a[3]=q2.w;
        }

        #pragma unroll 1
        for (int it = 0; it < NI; ++it) {
            asm volatile("" : "+v"(zero));
            const float*  W1z  = wlds + OFF_W1  + s * 64 + zero;
            const float*  W2Tz = wlds + OFF_W2T + s * 32 + zero;
            const float*  Cz   = wlds + OFF_C   + s * 32 + zero;
            const float4* tz   = tbuf + tid + zero;

            // H init from n-paired C
            f2 H2[2][D];
            #pragma unroll
            for (int nn = 0; nn < 2; ++nn) {
                #pragma unroll
                for (int dp = 0; dp < 4; ++dp) {
                    float4 cq = ld4(Cz + nn * 16 + dp * 4);
                    H2[nn][2 * dp]     = (f2){cq.x, cq.y};
                    H2[nn][2 * dp + 1] = (f2){cq.z, cq.w};
                }
            }
            // H2[nn][d] += sum_i E2[nn][i] * t[d][i]
            #pragma unroll
            for (int d = 0; d < D; ++d) {
                float4 ta = tz[(2 * d) * 256];
                float4 tb = tz[(2 * d + 1) * 256];
                #pragma unroll
                for (int nn = 0; nn < 2; ++nn) {
                    f2 acc = H2[nn][d];
                    acc = fma2(E2[nn][0], bc(ta.x), acc);
                    acc = fma2(E2[nn][1], bc(ta.y), acc);
                    acc = fma2(E2[nn][2], bc(ta.z), acc);
                    acc = fma2(E2[nn][3], bc(ta.w), acc);
                    acc = fma2(E2[nn][4], bc(tb.x), acc);
                    acc = fma2(E2[nn][5], bc(tb.y), acc);
                    acc = fma2(E2[nn][6], bc(tb.z), acc);
                    acc = fma2(E2[nn][7], bc(tb.w), acc);
                    H2[nn][d] = acc;
                }
            }

            // fused routing: per d compute r2 then accumulate into lg
            f2 lg2[2][NE];
            #pragma unroll
            for (int nn = 0; nn < 2; ++nn)
                #pragma unroll
                for (int e = 0; e < NE; ++e) lg2[nn][e] = bc(b2a[e]);

            #pragma unroll
            for (int d = 0; d < D; ++d) {
                float4 wa = ld4(W1z + d * 8);
                float4 wb = ld4(W1z + d * 8 + 4);
                float4 w2 = ld4(W2Tz + d * 4);
                #pragma unroll
                for (int nn = 0; nn < 2; ++nn) {
                    f2 acc = bc(b1a[d]);
                    acc = fma2(H2[nn][0], bc(wa.x), acc);
                    acc = fma2(H2[nn][1], bc(wa.y), acc);
                    acc = fma2(H2[nn][2], bc(wa.z), acc);
                    acc = fma2(H2[nn][3], bc(wa.w), acc);
                    acc = fma2(H2[nn][4], bc(wb.x), acc);
                    acc = fma2(H2[nn][5], bc(wb.y), acc);
                    acc = fma2(H2[nn][6], bc(wb.z), acc);
                    acc = fma2(H2[nn][7], bc(wb.w), acc);
                    f2 r2 = max2(acc, bc(0.f));
                    lg2[nn][0] = fma2(r2, bc(w2.x), lg2[nn][0]);
                    lg2[nn][1] = fma2(r2, bc(w2.y), lg2[nn][1]);
                    lg2[nn][2] = fma2(r2, bc(w2.z), lg2[nn][2]);
                    lg2[nn][3] = fma2(r2, bc(w2.w), lg2[nn][3]);
                }
            }

            // softmax over e (per n; n's packed in f2 lanes)
            f2 sm2[2][NE];
            #pragma unroll
            for (int nn = 0; nn < 2; ++nn) {
                f2 m2 = max2(max2(lg2[nn][0], lg2[nn][1]), max2(lg2[nn][2], lg2[nn][3]));
                f2 ee[NE];
                #pragma unroll
                for (int e = 0; e < NE; ++e) {
                    f2 t = lg2[nn][e] - m2;
                    ee[e] = (f2){ __expf(t.x), __expf(t.y) };
                }
                f2 s2 = (ee[0] + ee[1]) + (ee[2] + ee[3]);
                f2 inv2 = (f2){ __builtin_amdgcn_rcpf(s2.x), __builtin_amdgcn_rcpf(s2.y) };
                #pragma unroll
                for (int e = 0; e < NE; ++e) sm2[nn][e] = ee[e] * inv2;
            }

            // E2[nn][d] += sum_e sm2[nn][e] * H[e][d]
            #pragma unroll
            for (int d = 0; d < D; ++d) {
                #pragma unroll
                for (int nn = 0; nn < 2; ++nn) {
                    f2 acc = E2[nn][d];
                    acc = fma2(sm2[nn][0], bc(H2[0][d].x), acc);
                    acc = fma2(sm2[nn][1], bc(H2[0][d].y), acc);
                    acc = fma2(sm2[nn][2], bc(H2[1][d].x), acc);
                    acc = fma2(sm2[nn][3], bc(H2[1][d].y), acc);
                    E2[nn][d] = acc;
                }
            }
        }

        // post-stage LayerNorm (params from LDS; packed math)
        float lngv[8], lnbv[8];
        {
            float4 g0 = ld4(wlds + OFF_LN),     g1 = ld4(wlds + OFF_LN + 4);
            float4 b0 = ld4(wlds + OFF_LN + 8), b1 = ld4(wlds + OFF_LN + 12);
            lngv[0]=g0.x; lngv[1]=g0.y; lngv[2]=g0.z; lngv[3]=g0.w;
            lngv[4]=g1.x; lngv[5]=g1.y; lngv[6]=g1.z; lngv[7]=g1.w;
            lnbv[0]=b0.x; lnbv[1]=b0.y; lnbv[2]=b0.z; lnbv[3]=b0.w;
            lnbv[4]=b1.x; lnbv[5]=b1.y; lnbv[6]=b1.z; lnbv[7]=b1.w;
        }
        #pragma unroll
        for (int nn = 0; nn < 2; ++nn) {
            f2 s2 = (E2[nn][0] + E2[nn][1]) + (E2[nn][2] + E2[nn][3]);
            s2 = s2 + (E2[nn][4] + E2[nn][5]) + (E2[nn][6] + E2[nn][7]);
            f2 m2 = s2 * bc(0.125f);
            f2 v2 = bc(0.f);
            #pragma unroll
            for (int d = 0; d < D; ++d) { f2 c = E2[nn][d] - m2; v2 = fma2(c, c, v2); }
            v2 = v2 * bc(0.125f);
            f2 inv2 = (f2){ __builtin_amdgcn_rsqf(v2.x + LN_EPS),
                            __builtin_amdgcn_rsqf(v2.y + LN_EPS) };
            #pragma unroll
            for (int d = 0; d < D; ++d)
                E2[nn][d] = fma2((E2[nn][d] - m2) * inv2, bc(lngv[d]), bc(lnbv[d]));
        }
    }

    // ---- final mixing (one-time global weights; scalar epilogue) ----
    float lgf[NE];
    #pragma unroll
    for (int e = 0; e < NE; ++e) {
        float a0 = bout[e], a1 = 0.f;
        #pragma unroll
        for (int d = 0; d < D; ++d) {
            a0 = fmaf(E2[0][d].x, Wout[e * 32 + 0 * D + d], a0);
            a1 = fmaf(E2[0][d].y, Wout[e * 32 + 1 * D + d], a1);
            a0 = fmaf(E2[1][d].x, Wout[e * 32 + 2 * D + d], a0);
            a1 = fmaf(E2[1][d].y, Wout[e * 32 + 3 * D + d], a1);
        }
        lgf[e] = a0 + a1;
    }
    float mx = fmaxf(fmaxf(lgf[0], lgf[1]), fmaxf(lgf[2], lgf[3]));
    float w0 = __expf(lgf[0] - mx), w1 = __expf(lgf[1] - mx);
    float w2 = __expf(lgf[2] - mx), w3 = __expf(lgf[3] - mx);
    float winv = __builtin_amdgcn_rcpf((w0 + w1) + (w2 + w3));
    w0 *= winv; w1 *= winv; w2 *= winv; w3 *= winv;

    float z[D];
    #pragma unroll
    for (int d = 0; d < D; ++d) {
        float a0 = w0 * E2[0][d].x;
        float a1 = w1 * E2[0][d].y;
        a0 = fmaf(w2, E2[1][d].x, a0);
        a1 = fmaf(w3, E2[1][d].y, a1);
        z[d] = a0 + a1;
    }
    float zm = 0.f;
    #pragma unroll
    for (int d = 0; d < D; ++d) zm += z[d];
    zm *= (1.f / D);
    float zv = 0.f;
    #pragma unroll
    for (int d = 0; d < D; ++d) { float c = z[d] - zm; zv = fmaf(c, c, zv); }
    zv *= (1.f / D);
    float zinv = __builtin_amdgcn_rsqf(zv + LN_EPS);
    #pragma unroll
    for (int d = 0; d < D; ++d)
        z[d] = (z[d] - zm) * zinv * fg[d] + fb[d];

    // heads
    float zout[19];
    #pragma unroll
    for (int k = 0; k < 18; ++k) {
        float a0 = bcst[k], a1 = 0.f;
        #pragma unroll
        for (int d = 0; d < D; d += 2) {
            a0 = fmaf(z[d],     Wcst[k * D + d],     a0);
            a1 = fmaf(z[d + 1], Wcst[k * D + d + 1], a1);
        }
        zout[k] = a0 + a1;
    }
    {
        float a0 = bcl[0], a1 = 0.f;
        #pragma unroll
        for (int d = 0; d < D; d += 2) {
            a0 = fmaf(z[d],     Wcl[d],     a0);
            a1 = fmaf(z[d + 1], Wcl[d + 1], a1);
        }
        zout[18] = a0 + a1;
    }

    // tbuf is dead; reuse as souts
    __syncthreads();
    float* souts = reinterpret_cast<float*>(tbuf);
    if (active) {
        #pragma unroll
        for (int k = 0; k < 19; ++k) souts[tid * 19 + k] = zout[k];
    }
    __syncthreads();

    // coalesced writeback of this block's 256x19 outputs
    const int base = blockIdx.x * 256;
    int nrows = B - base;
    if (nrows > 256) nrows = 256;
    if (nrows > 0) {
        const int cnt = nrows * 19;
        for (int i = tid; i < cnt; i += 256)
            out[(size_t)base * 19 + i] = souts[i];
    }
}

extern "C" void kernel_launch(void* const* d_in, const int* in_sizes, int n_in,
                              void* d_out, int out_size, void* d_ws, size_t ws_size,
                              hipStream_t stream) {
    const float* cl     = (const float*)d_in[0];
    const float* cd     = (const float*)d_in[1];
    const float* re_log = (const float*)d_in[2];
    const float* mach   = (const float*)d_in[3];
    const float* alpha  = (const float*)d_in[4];
    const float* u      = (const float*)d_in[5];
    const float* We     = (const float*)d_in[6];
    const float* be     = (const float*)d_in[7];
    const float* Bmat   = (const float*)d_in[8];
    const float* Wproj  = (const float*)d_in[9];
    const float* bproj  = (const float*)d_in[10];
    const float* Wr1    = (const float*)d_in[11];
    const float* br1    = (const float*)d_in[12];
    const float* Wr2    = (const float*)d_in[13];
    const float* br2    = (const float*)d_in[14];
    const float* ln_g   = (const float*)d_in[15];
    const float* ln_b   = (const float*)d_in[16];
    const float* Wout   = (const float*)d_in[17];
    const float* bout   = (const float*)d_in[18];
    const float* fg     = (const float*)d_in[19];
    const float* fb     = (const float*)d_in[20];
    const float* Wcst   = (const float*)d_in[21];
    const float* bcst   = (const float*)d_in[22];
    const float* Wcl    = (const float*)d_in[23];
    const float* bcl    = (const float*)d_in[24];

    float* Cpre = (float*)d_ws;   // 96 floats (n-paired layout)
    const int B = in_sizes[0];

    hipLaunchKernelGGL(precompute_C_kernel, dim3(1), dim3(128), 0, stream,
                       Bmat, Wproj, bproj, Cpre);

    const int blocks = (B + 255) / 256;
    hipLaunchKernelGGL(whisp_kernel, dim3(blocks), dim3(256), 0, stream,
                       cl, cd, re_log, mach, alpha, u, We, be, Wproj,
                       Wr1, br1, Wr2, br2, ln_g, ln_b, Wout, bout, fg, fb,
                       Wcst, bcst, Wcl, bcl, Cpre, (float*)d_out, B);
}